// Round 2
// baseline (729.080 us; speedup 1.0000x reference)
//
#include <hip/hip_runtime.h>
#include <hip/hip_bf16.h>
#include <math.h>

#define N_ENT  50000
#define N_REL  500
#define N_EDGE 800000
#define D      100
#define ALPHA  0.2f

// ---------------------------------------------------------------------------
// K1: Y = X @ W   (X: [N,100], W: [100,100], Y: [N,100])
// one block per row; threads 0..99 active; W column reads coalesced across j
// ---------------------------------------------------------------------------
__global__ void proj_kernel(const float* __restrict__ X,
                            const float* __restrict__ W,
                            float* __restrict__ Y, int N) {
    __shared__ float row[D];
    int n = blockIdx.x;
    if (n >= N) return;
    int tid = threadIdx.x;
    if (tid < D) row[tid] = X[n * D + tid];
    __syncthreads();
    if (tid < D) {
        float acc = 0.f;
        #pragma unroll
        for (int k = 0; k < D; ++k)
            acc = fmaf(row[k], W[k * D + tid], acc);
        Y[n * D + tid] = acc;
    }
}

// ---------------------------------------------------------------------------
// K2: per-edge TransE score + segment max (one 64-lane wave per edge)
// ---------------------------------------------------------------------------
__global__ void edge_score_kernel(const float* __restrict__ ent,
                                  const float* __restrict__ rel,
                                  const int* __restrict__ h_idx,
                                  const int* __restrict__ t_idx,
                                  const int* __restrict__ etype,
                                  float* __restrict__ score,
                                  float* __restrict__ segmax) {
    int edge = blockIdx.x * 4 + (threadIdx.x >> 6);
    int lane = threadIdx.x & 63;
    if (edge >= N_EDGE) return;
    int h = h_idx[edge], t = t_idx[edge], r = etype[edge];
    const float* eh = ent + (long)h * D;
    const float* et = ent + (long)t * D;
    const float* er = rel + (long)r * D;
    float s = 0.f;
    for (int d = lane; d < D; d += 64) {
        float df = eh[d] + er[d] - et[d];
        s = fmaf(df, df, s);
    }
    #pragma unroll
    for (int off = 32; off; off >>= 1)
        s += __shfl_xor(s, off, 64);
    if (lane == 0) {
        float sc = sqrtf(s);
        sc = (sc >= 0.f) ? sc : ALPHA * sc;   // leaky_relu (identity: sc>=0)
        score[edge] = sc;
        // scores >= 0 -> int compare == float compare; segmax pre-zeroed
        atomicMax((int*)(segmax + h), __float_as_int(sc));
    }
}

// ---------------------------------------------------------------------------
// K3: ex = exp(score - segmax[h]); denom[h] += ex  (scalar per edge)
// ---------------------------------------------------------------------------
__global__ void edge_exp_kernel(const float* __restrict__ score,
                                const float* __restrict__ segmax,
                                const int* __restrict__ h_idx,
                                float* __restrict__ denom) {
    int e = blockIdx.x * blockDim.x + threadIdx.x;
    if (e >= N_EDGE) return;
    int h = h_idx[e];
    float ex = __expf(score[e] - segmax[h]);
    atomicAdd(denom + h, ex);
}

// ---------------------------------------------------------------------------
// K4: out[h,:] += (ent[t,:] - rel[r,:]) * att   (one wave per edge, atomics)
// ---------------------------------------------------------------------------
__global__ void edge_msg_kernel(const float* __restrict__ ent,
                                const float* __restrict__ rel,
                                const float* __restrict__ score,
                                const float* __restrict__ segmax,
                                const float* __restrict__ denom,
                                const int* __restrict__ h_idx,
                                const int* __restrict__ t_idx,
                                const int* __restrict__ etype,
                                float* __restrict__ out) {
    int edge = blockIdx.x * 4 + (threadIdx.x >> 6);
    int lane = threadIdx.x & 63;
    if (edge >= N_EDGE) return;
    int h = h_idx[edge], t = t_idx[edge], r = etype[edge];
    float att = __expf(score[edge] - segmax[h]) / (denom[h] + 1e-16f);
    const float* et = ent + (long)t * D;
    const float* er = rel + (long)r * D;
    float* oh = out + (long)h * D;
    for (int d = lane; d < D; d += 64)
        atomicAdd(oh + d, (et[d] - er[d]) * att);
}

// ---------------------------------------------------------------------------
// K5: in-place ELU
// ---------------------------------------------------------------------------
__global__ void elu_kernel(float* __restrict__ out, int n) {
    int i = blockIdx.x * blockDim.x + threadIdx.x;
    if (i >= n) return;
    float x = out[i];
    out[i] = (x > 0.f) ? x : expm1f(x);
}

extern "C" void kernel_launch(void* const* d_in, const int* in_sizes, int n_in,
                              void* d_out, int out_size, void* d_ws, size_t ws_size,
                              hipStream_t stream) {
    const float* entity_emb = (const float*)d_in[0];   // [N_ENT, D]
    const float* rel_emb    = (const float*)d_in[1];   // [N_REL, D]
    const float* W          = (const float*)d_in[2];   // [D, D]
    const int*   edge_index = (const int*)d_in[3];     // [2, N_EDGE]
    const int*   edge_type  = (const int*)d_in[4];     // [N_EDGE]
    float*       out        = (float*)d_out;           // [N_ENT, D]

    const int* h_idx = edge_index;             // row 0: head/destination
    const int* t_idx = edge_index + N_EDGE;    // row 1: tail/source

    // workspace layout (floats)
    float* ent    = (float*)d_ws;                       // N_ENT*D   = 5,000,000
    float* rel    = ent    + (size_t)N_ENT * D;         // N_REL*D   =    50,000
    float* score  = rel    + (size_t)N_REL * D;         // N_EDGE    =   800,000
    float* segmax = score  + N_EDGE;                    // N_ENT     =    50,000
    float* denom  = segmax + N_ENT;                     // N_ENT     =    50,000

    // zero: out accumulator + segmax + denom (zero bits == 0.0f)
    hipMemsetAsync(d_out, 0, (size_t)N_ENT * D * sizeof(float), stream);
    hipMemsetAsync(segmax, 0, (size_t)2 * N_ENT * sizeof(float), stream);

    // K1: projections
    proj_kernel<<<N_ENT, 128, 0, stream>>>(entity_emb, W, ent, N_ENT);
    proj_kernel<<<N_REL, 128, 0, stream>>>(rel_emb, W, rel, N_REL);

    // K2: edge scores + segment max
    edge_score_kernel<<<(N_EDGE + 3) / 4, 256, 0, stream>>>(
        ent, rel, h_idx, t_idx, edge_type, score, segmax);

    // K3: exp + denom
    edge_exp_kernel<<<(N_EDGE + 255) / 256, 256, 0, stream>>>(
        score, segmax, h_idx, denom);

    // K4: attention-weighted message scatter
    edge_msg_kernel<<<(N_EDGE + 3) / 4, 256, 0, stream>>>(
        ent, rel, score, segmax, denom, h_idx, t_idx, edge_type, out);

    // K5: ELU
    elu_kernel<<<(N_ENT * D + 255) / 256, 256, 0, stream>>>(out, N_ENT * D);
}

// Round 3
// 497.316 us; speedup vs baseline: 1.4660x; 1.4660x over previous
//
#include <hip/hip_runtime.h>
#include <math.h>

#define N_ENT  50000
#define N_REL  500
#define N_EDGE 800000
#define D      100
#define D2     50          // float2 lanes per row
#define ALPHA  0.2f

#define SCAN_B 256
#define NBLK_SCAN ((N_ENT + SCAN_B - 1) / SCAN_B)   // 196

// ---------------------------------------------------------------------------
// K1: Y = X @ W with W staged in LDS; 32 rows per block, 128 threads
// ---------------------------------------------------------------------------
#define PROJ_ROWS 32
__global__ void proj_kernel(const float* __restrict__ X,
                            const float* __restrict__ W,
                            float* __restrict__ Y, int N) {
    __shared__ float Wl[D * D];   // 40 KB
    __shared__ float xr[D];
    int tid = threadIdx.x;        // 128
    for (int i = tid; i < D * D; i += 128) Wl[i] = W[i];
    int base = blockIdx.x * PROJ_ROWS;
    __syncthreads();
    for (int r = 0; r < PROJ_ROWS; ++r) {
        int row = base + r;               // block-uniform
        if (row >= N) break;
        if (tid < D) xr[tid] = X[row * D + tid];
        __syncthreads();
        if (tid < D) {
            float acc = 0.f;
            #pragma unroll
            for (int k = 0; k < D; ++k)
                acc = fmaf(xr[k], Wl[k * D + tid], acc);
            Y[row * D + tid] = acc;
        }
        __syncthreads();
    }
}

// ---------------------------------------------------------------------------
// CSR build: degree count -> block scan (3 kernels) -> fill buckets
// ---------------------------------------------------------------------------
__global__ void degree_kernel(const int* __restrict__ h_idx, int* __restrict__ deg) {
    int e = blockIdx.x * blockDim.x + threadIdx.x;
    if (e < N_EDGE) atomicAdd(&deg[h_idx[e]], 1);
}

__global__ void scan1_kernel(const int* __restrict__ deg, int* __restrict__ bsum) {
    __shared__ int s[SCAN_B];
    int i = blockIdx.x * SCAN_B + threadIdx.x;
    s[threadIdx.x] = (i < N_ENT) ? deg[i] : 0;
    __syncthreads();
    for (int off = SCAN_B / 2; off; off >>= 1) {
        if (threadIdx.x < off) s[threadIdx.x] += s[threadIdx.x + off];
        __syncthreads();
    }
    if (threadIdx.x == 0) bsum[blockIdx.x] = s[0];
}

__global__ void scan2_kernel(const int* __restrict__ bsum, int* __restrict__ boff) {
    __shared__ int s[SCAN_B];
    int tid = threadIdx.x;
    int v = (tid < NBLK_SCAN) ? bsum[tid] : 0;
    s[tid] = v;
    __syncthreads();
    for (int off = 1; off < SCAN_B; off <<= 1) {
        int x = (tid >= off) ? s[tid - off] : 0;
        __syncthreads();
        s[tid] += x;
        __syncthreads();
    }
    if (tid < NBLK_SCAN) boff[tid] = s[tid] - v;   // exclusive
}

__global__ void scan3_kernel(const int* __restrict__ deg, const int* __restrict__ boff,
                             int* __restrict__ rowptr, int* __restrict__ cursor) {
    __shared__ int s[SCAN_B];
    int tid = threadIdx.x;
    int i = blockIdx.x * SCAN_B + tid;
    int v = (i < N_ENT) ? deg[i] : 0;
    s[tid] = v;
    __syncthreads();
    for (int off = 1; off < SCAN_B; off <<= 1) {
        int x = (tid >= off) ? s[tid - off] : 0;
        __syncthreads();
        s[tid] += x;
        __syncthreads();
    }
    int excl = s[tid] - v + boff[blockIdx.x];
    if (i < N_ENT) { rowptr[i] = excl; cursor[i] = excl; }
    if (i == N_ENT - 1) rowptr[N_ENT] = excl + v;
}

__global__ void fill_kernel(const int* __restrict__ h_idx, const int* __restrict__ t_idx,
                            const int* __restrict__ etype, int* __restrict__ cursor,
                            int* __restrict__ t_sorted, int* __restrict__ r_sorted) {
    int e = blockIdx.x * blockDim.x + threadIdx.x;
    if (e >= N_EDGE) return;
    int h = h_idx[e];
    int pos = atomicAdd(&cursor[h], 1);
    t_sorted[pos] = t_idx[e];
    r_sorted[pos] = etype[e];
}

// ---------------------------------------------------------------------------
// Fused per-head kernel: one 64-lane wave per head node.
// Online softmax over the head's edges; single gather pass per edge.
//   v = rel[r] - ent[t];  score = ||ent[h] + v||;  msg = -v
//   out[h] = ELU( (sum ex*msg) / (sum ex + 1e-16) )
// ---------------------------------------------------------------------------
__global__ void fused_kernel(const float* __restrict__ ent, const float* __restrict__ rel,
                             const int* __restrict__ rowptr,
                             const int* __restrict__ t_sorted, const int* __restrict__ r_sorted,
                             float* __restrict__ out) {
    int head = blockIdx.x * 4 + (threadIdx.x >> 6);
    int lane = threadIdx.x & 63;
    if (head >= N_ENT) return;
    int beg = rowptr[head], end = rowptr[head + 1];

    float2 eh = make_float2(0.f, 0.f);
    if (lane < D2) eh = ((const float2*)(ent + (size_t)head * D))[lane];

    float  m   = -INFINITY;
    float  den = 0.f;
    float2 acc = make_float2(0.f, 0.f);

    for (int i = beg; i < end; ++i) {
        int t = t_sorted[i];
        int r = r_sorted[i];
        float2 v = make_float2(0.f, 0.f);      // rel - ent_t
        if (lane < D2) {
            float2 et = ((const float2*)(ent + (size_t)t * D))[lane];
            float2 er = ((const float2*)(rel + (size_t)r * D))[lane];
            v = make_float2(er.x - et.x, er.y - et.y);
        }
        float dx = eh.x + v.x, dy = eh.y + v.y;
        float s = fmaf(dx, dx, dy * dy);       // lanes >= 50 contribute 0
        #pragma unroll
        for (int off = 32; off; off >>= 1) s += __shfl_xor(s, off, 64);
        float sc = sqrtf(s);                   // leaky_relu identity (sc >= 0)

        float mn    = fmaxf(m, sc);
        float scale = __expf(m - mn);          // first iter: exp(-inf) = 0
        float ex    = __expf(sc - mn);
        den   = den * scale + ex;
        acc.x = acc.x * scale - v.x * ex;      // msg = ent_t - rel = -v
        acc.y = acc.y * scale - v.y * ex;
        m = mn;
    }

    float inv = 1.f / (den + 1e-16f);
    float ox = acc.x * inv, oy = acc.y * inv;
    ox = ox > 0.f ? ox : expm1f(ox);           // ELU
    oy = oy > 0.f ? oy : expm1f(oy);
    if (lane < D2)
        ((float2*)(out + (size_t)head * D))[lane] = make_float2(ox, oy);
}

extern "C" void kernel_launch(void* const* d_in, const int* in_sizes, int n_in,
                              void* d_out, int out_size, void* d_ws, size_t ws_size,
                              hipStream_t stream) {
    const float* entity_emb = (const float*)d_in[0];   // [N_ENT, D]
    const float* rel_emb    = (const float*)d_in[1];   // [N_REL, D]
    const float* W          = (const float*)d_in[2];   // [D, D]
    const int*   edge_index = (const int*)d_in[3];     // [2, N_EDGE]
    const int*   edge_type  = (const int*)d_in[4];     // [N_EDGE]
    float*       out        = (float*)d_out;           // [N_ENT, D]

    const int* h_idx = edge_index;             // row 0: head/destination
    const int* t_idx = edge_index + N_EDGE;    // row 1: tail/source

    // workspace layout (~27.2 MB)
    float* ent      = (float*)d_ws;                    // 5,000,000 f
    float* rel      = ent + (size_t)N_ENT * D;         //    50,000 f
    int*   deg      = (int*)(rel + (size_t)N_REL * D); //    50,000 i
    int*   rowptr   = deg + N_ENT;                     //    50,001 i
    int*   cursor   = rowptr + (N_ENT + 1);            //    50,000 i
    int*   bsum     = cursor + N_ENT;                  //       256 i
    int*   boff     = bsum + SCAN_B;                   //       256 i
    int*   t_sorted = boff + SCAN_B;                   //   800,000 i
    int*   r_sorted = t_sorted + N_EDGE;               //   800,000 i

    hipMemsetAsync(deg, 0, N_ENT * sizeof(int), stream);

    // projections (W staged in LDS)
    proj_kernel<<<(N_ENT + PROJ_ROWS - 1) / PROJ_ROWS, 128, 0, stream>>>(entity_emb, W, ent, N_ENT);
    proj_kernel<<<(N_REL + PROJ_ROWS - 1) / PROJ_ROWS, 128, 0, stream>>>(rel_emb, W, rel, N_REL);

    // CSR build
    degree_kernel<<<(N_EDGE + 255) / 256, 256, 0, stream>>>(h_idx, deg);
    scan1_kernel<<<NBLK_SCAN, SCAN_B, 0, stream>>>(deg, bsum);
    scan2_kernel<<<1, SCAN_B, 0, stream>>>(bsum, boff);
    scan3_kernel<<<NBLK_SCAN, SCAN_B, 0, stream>>>(deg, boff, rowptr, cursor);
    fill_kernel<<<(N_EDGE + 255) / 256, 256, 0, stream>>>(h_idx, t_idx, edge_type,
                                                          cursor, t_sorted, r_sorted);

    // fused score + online-softmax + message + ELU (one wave per head)
    fused_kernel<<<(N_ENT + 3) / 4, 256, 0, stream>>>(ent, rel, rowptr,
                                                      t_sorted, r_sorted, out);
}

// Round 5
// 416.664 us; speedup vs baseline: 1.7498x; 1.1936x over previous
//
#include <hip/hip_runtime.h>
#include <math.h>

#define N_ENT  50000
#define N_REL  500
#define N_EDGE 800000
#define D      100
#define D2     50          // float2 lanes per row
#define ALPHA  0.2f

#define SCAN_B 256
#define NBLK_SCAN ((N_ENT + SCAN_B - 1) / SCAN_B)   // 196

// ---------------------------------------------------------------------------
// K1: Y = X @ W. No LDS, no barriers. 256 threads: tid<200 active.
//   c = tid%100 (output col), half = tid/100 (row group).
//   Each thread: 8 rows x 1 col, 8 independent FMA chains.
//   X loads: float4, same addr across the 100 lanes of a row -> L1 broadcast.
//   W loads: coalesced 400B across lanes, W is L1/L2 resident (40 KB).
// ---------------------------------------------------------------------------
#define PROJ_RPT 8
__global__ __launch_bounds__(256) void proj_kernel(const float* __restrict__ X,
                                                   const float* __restrict__ W,
                                                   float* __restrict__ Y, int N) {
    int tid = threadIdx.x;
    if (tid >= 200) return;
    int half = tid / 100;
    int c    = tid % 100;
    int rbase = blockIdx.x * (2 * PROJ_RPT) + half * PROJ_RPT;

    float acc[PROJ_RPT];
    #pragma unroll
    for (int r = 0; r < PROJ_RPT; ++r) acc[r] = 0.f;

    for (int k0 = 0; k0 < D; k0 += 4) {
        float4 xv[PROJ_RPT];
        #pragma unroll
        for (int r = 0; r < PROJ_RPT; ++r) {
            int row = rbase + r;
            xv[r] = (row < N) ? *(const float4*)(X + (size_t)row * D + k0)
                              : make_float4(0.f, 0.f, 0.f, 0.f);
        }
        #pragma unroll
        for (int kk = 0; kk < 4; ++kk) {
            float w = W[(k0 + kk) * D + c];
            #pragma unroll
            for (int r = 0; r < PROJ_RPT; ++r) {
                float x = (kk == 0) ? xv[r].x : (kk == 1) ? xv[r].y
                        : (kk == 2) ? xv[r].z : xv[r].w;
                acc[r] = fmaf(x, w, acc[r]);
            }
        }
    }
    #pragma unroll
    for (int r = 0; r < PROJ_RPT; ++r) {
        int row = rbase + r;
        if (row < N) Y[(size_t)row * D + c] = acc[r];
    }
}

// ---------------------------------------------------------------------------
// CSR build: degree count -> block scan (3 kernels) -> fill buckets
// ---------------------------------------------------------------------------
__global__ void degree_kernel(const int* __restrict__ h_idx, int* __restrict__ deg) {
    int e = blockIdx.x * blockDim.x + threadIdx.x;
    if (e < N_EDGE) atomicAdd(&deg[h_idx[e]], 1);
}

__global__ void scan1_kernel(const int* __restrict__ deg, int* __restrict__ bsum) {
    __shared__ int s[SCAN_B];
    int i = blockIdx.x * SCAN_B + threadIdx.x;
    s[threadIdx.x] = (i < N_ENT) ? deg[i] : 0;
    __syncthreads();
    for (int off = SCAN_B / 2; off; off >>= 1) {
        if (threadIdx.x < off) s[threadIdx.x] += s[threadIdx.x + off];
        __syncthreads();
    }
    if (threadIdx.x == 0) bsum[blockIdx.x] = s[0];
}

__global__ void scan2_kernel(const int* __restrict__ bsum, int* __restrict__ boff) {
    __shared__ int s[SCAN_B];
    int tid = threadIdx.x;
    int v = (tid < NBLK_SCAN) ? bsum[tid] : 0;
    s[tid] = v;
    __syncthreads();
    for (int off = 1; off < SCAN_B; off <<= 1) {
        int x = (tid >= off) ? s[tid - off] : 0;
        __syncthreads();
        s[tid] += x;
        __syncthreads();
    }
    if (tid < NBLK_SCAN) boff[tid] = s[tid] - v;   // exclusive
}

__global__ void scan3_kernel(const int* __restrict__ deg, const int* __restrict__ boff,
                             int* __restrict__ rowptr, int* __restrict__ cursor) {
    __shared__ int s[SCAN_B];
    int tid = threadIdx.x;
    int i = blockIdx.x * SCAN_B + tid;
    int v = (i < N_ENT) ? deg[i] : 0;
    s[tid] = v;
    __syncthreads();
    for (int off = 1; off < SCAN_B; off <<= 1) {
        int x = (tid >= off) ? s[tid - off] : 0;
        __syncthreads();
        s[tid] += x;
        __syncthreads();
    }
    int excl = s[tid] - v + boff[blockIdx.x];
    if (i < N_ENT) { rowptr[i] = excl; cursor[i] = excl; }
    if (i == N_ENT - 1) rowptr[N_ENT] = excl + v;
}

__global__ void fill_kernel(const int* __restrict__ h_idx, const int* __restrict__ t_idx,
                            const int* __restrict__ etype, int* __restrict__ cursor,
                            int* __restrict__ t_sorted, int* __restrict__ r_sorted) {
    int e = blockIdx.x * blockDim.x + threadIdx.x;
    if (e >= N_EDGE) return;
    int h = h_idx[e];
    int pos = atomicAdd(&cursor[h], 1);
    t_sorted[pos] = t_idx[e];
    r_sorted[pos] = etype[e];
}

// ---------------------------------------------------------------------------
// Fused per-head kernel: one 64-lane wave per head node, online softmax,
// unroll-by-2 so the two edges' gathers issue before either serial chain.
// ---------------------------------------------------------------------------
__device__ __forceinline__ float edge_reduce(float2 eh, float2 v) {
    float dx = eh.x + v.x, dy = eh.y + v.y;
    float s = fmaf(dx, dx, dy * dy);
    #pragma unroll
    for (int off = 32; off; off >>= 1) s += __shfl_xor(s, off, 64);
    return sqrtf(s);                       // leaky_relu identity (s >= 0)
}

__global__ void fused_kernel(const float* __restrict__ ent, const float* __restrict__ rel,
                             const int* __restrict__ rowptr,
                             const int* __restrict__ t_sorted, const int* __restrict__ r_sorted,
                             float* __restrict__ out) {
    int head = blockIdx.x * 4 + (threadIdx.x >> 6);
    int lane = threadIdx.x & 63;
    if (head >= N_ENT) return;
    int beg = rowptr[head], end = rowptr[head + 1];

    float2 eh = make_float2(0.f, 0.f);
    if (lane < D2) eh = ((const float2*)(ent + (size_t)head * D))[lane];

    float  m   = -INFINITY;
    float  den = 0.f;
    float2 acc = make_float2(0.f, 0.f);

    int i = beg;
    for (; i + 1 < end; i += 2) {
        int t0 = t_sorted[i],     r0 = r_sorted[i];
        int t1 = t_sorted[i + 1], r1 = r_sorted[i + 1];
        float2 v0 = make_float2(0.f, 0.f), v1 = make_float2(0.f, 0.f);
        if (lane < D2) {
            float2 et0 = ((const float2*)(ent + (size_t)t0 * D))[lane];
            float2 er0 = ((const float2*)(rel + (size_t)r0 * D))[lane];
            float2 et1 = ((const float2*)(ent + (size_t)t1 * D))[lane];
            float2 er1 = ((const float2*)(rel + (size_t)r1 * D))[lane];
            v0 = make_float2(er0.x - et0.x, er0.y - et0.y);
            v1 = make_float2(er1.x - et1.x, er1.y - et1.y);
        }
        float sc0 = edge_reduce(eh, v0);
        float sc1 = edge_reduce(eh, v1);

        float mn    = fmaxf(m, sc0);
        float scale = __expf(m - mn);
        float ex    = __expf(sc0 - mn);
        den   = den * scale + ex;
        acc.x = acc.x * scale - v0.x * ex;
        acc.y = acc.y * scale - v0.y * ex;
        m = mn;

        mn    = fmaxf(m, sc1);
        scale = __expf(m - mn);
        ex    = __expf(sc1 - mn);
        den   = den * scale + ex;
        acc.x = acc.x * scale - v1.x * ex;
        acc.y = acc.y * scale - v1.y * ex;
        m = mn;
    }
    if (i < end) {
        int t = t_sorted[i], r = r_sorted[i];
        float2 v = make_float2(0.f, 0.f);
        if (lane < D2) {
            float2 et = ((const float2*)(ent + (size_t)t * D))[lane];
            float2 er = ((const float2*)(rel + (size_t)r * D))[lane];
            v = make_float2(er.x - et.x, er.y - et.y);
        }
        float sc = edge_reduce(eh, v);
        float mn    = fmaxf(m, sc);
        float scale = __expf(m - mn);
        float ex    = __expf(sc - mn);
        den   = den * scale + ex;
        acc.x = acc.x * scale - v.x * ex;
        acc.y = acc.y * scale - v.y * ex;
        m = mn;
    }

    float inv = 1.f / (den + 1e-16f);
    float ox = acc.x * inv, oy = acc.y * inv;
    ox = ox > 0.f ? ox : expm1f(ox);           // ELU
    oy = oy > 0.f ? oy : expm1f(oy);
    if (lane < D2)
        ((float2*)(out + (size_t)head * D))[lane] = make_float2(ox, oy);
}

extern "C" void kernel_launch(void* const* d_in, const int* in_sizes, int n_in,
                              void* d_out, int out_size, void* d_ws, size_t ws_size,
                              hipStream_t stream) {
    const float* entity_emb = (const float*)d_in[0];   // [N_ENT, D]
    const float* rel_emb    = (const float*)d_in[1];   // [N_REL, D]
    const float* W          = (const float*)d_in[2];   // [D, D]
    const int*   edge_index = (const int*)d_in[3];     // [2, N_EDGE]
    const int*   edge_type  = (const int*)d_in[4];     // [N_EDGE]
    float*       out        = (float*)d_out;           // [N_ENT, D]

    const int* h_idx = edge_index;             // row 0: head/destination
    const int* t_idx = edge_index + N_EDGE;    // row 1: tail/source

    // workspace layout (~27.2 MB)
    float* ent      = (float*)d_ws;                    // 5,000,000 f
    float* rel      = ent + (size_t)N_ENT * D;         //    50,000 f
    int*   deg      = (int*)(rel + (size_t)N_REL * D); //    50,000 i
    int*   rowptr   = deg + N_ENT;                     //    50,001 i
    int*   cursor   = rowptr + (N_ENT + 1);            //    50,000 i
    int*   bsum     = cursor + N_ENT;                  //       256 i
    int*   boff     = bsum + SCAN_B;                   //       256 i
    int*   t_sorted = boff + SCAN_B;                   //   800,000 i
    int*   r_sorted = t_sorted + N_EDGE;               //   800,000 i

    hipMemsetAsync(deg, 0, N_ENT * sizeof(int), stream);

    // projections
    proj_kernel<<<(N_ENT + 2 * PROJ_RPT - 1) / (2 * PROJ_RPT), 256, 0, stream>>>(
        entity_emb, W, ent, N_ENT);
    proj_kernel<<<(N_REL + 2 * PROJ_RPT - 1) / (2 * PROJ_RPT), 256, 0, stream>>>(
        rel_emb, W, rel, N_REL);

    // CSR build
    degree_kernel<<<(N_EDGE + 255) / 256, 256, 0, stream>>>(h_idx, deg);
    scan1_kernel<<<NBLK_SCAN, SCAN_B, 0, stream>>>(deg, bsum);
    scan2_kernel<<<1, SCAN_B, 0, stream>>>(bsum, boff);
    scan3_kernel<<<NBLK_SCAN, SCAN_B, 0, stream>>>(deg, boff, rowptr, cursor);
    fill_kernel<<<(N_EDGE + 255) / 256, 256, 0, stream>>>(h_idx, t_idx, edge_type,
                                                          cursor, t_sorted, r_sorted);

    // fused score + online-softmax + message + ELU (one wave per head)
    fused_kernel<<<(N_ENT + 3) / 4, 256, 0, stream>>>(ent, rel, rowptr,
                                                      t_sorted, r_sorted, out);
}